// Round 6
// baseline (202.715 us; speedup 1.0000x reference)
//
#include <hip/hip_runtime.h>
#include <hip/hip_bf16.h>

// Problem constants
#define BB 2
#define SS 2048
#define HH 1024
#define NH 16
#define DD 64
#define H3 3072
#define MM (BB*SS)   // 4096 rows

typedef unsigned short u16;
typedef unsigned int u32;
typedef __attribute__((ext_vector_type(8))) short bf16x8;
typedef __attribute__((ext_vector_type(4))) float f32x4;

__device__ __forceinline__ u16 f2bf(float f) {
    union { float f; u32 u; } v; v.f = f;
    u32 u = v.u;
    u += 0x7fffu + ((u >> 16) & 1u);   // RNE
    return (u16)(u >> 16);
}
__device__ __forceinline__ float bf2f(u16 h) {
    union { u32 u; float f; } v; v.u = ((u32)h) << 16;
    return v.f;
}
__device__ __forceinline__ u32 pack2bf(float a, float b) {
    __hip_bfloat162 h = __float22bfloat162_rn(float2{a, b});
    u32 u; __builtin_memcpy(&u, &h, 4);
    return u;
}
// async global->LDS, 16B/lane; LDS dest = wave-uniform base + lane*16B.
__device__ __forceinline__ void gl_lds16(const void* g, void* l) {
    __builtin_amdgcn_global_load_lds(
        (const __attribute__((address_space(1))) u32*)g,
        (__attribute__((address_space(3))) u32*)l, 16, 0, 0);
}
// inverse of the K row bit-permutation Rp (g -> R): R4=g2 R3=g4 R2=g3, rest id.
// ginv(R): g = (R5,R3,R2,R4,R1,R0).  Verified: ginv(Rp(g)) == g.
__device__ __forceinline__ int ginv(int R) {
    return (R & 35) | ((R & 8) << 1) | ((R & 4) << 1) | ((R & 16) >> 2);
}

// ---------------------------------------------------------------------------
// fp32 -> bf16 bulk convert, three buffers per launch
// ---------------------------------------------------------------------------
__global__ void cvt3bf(const float4* __restrict__ s0, uint2* __restrict__ d0, int n0,
                       const float4* __restrict__ s1, uint2* __restrict__ d1, int n1,
                       const float4* __restrict__ s2, uint2* __restrict__ d2, int n2) {
    int i = blockIdx.x * blockDim.x + threadIdx.x;
    const int tot = n0 + n1 + n2;
    for (; i < tot; i += gridDim.x * blockDim.x) {
        const float4* s; uint2* d; int j;
        if (i < n0)            { s = s0; d = d0; j = i; }
        else if (i < n0 + n1)  { s = s1; d = d1; j = i - n0; }
        else                   { s = s2; d = d2; j = i - n0 - n1; }
        float4 v = s[j];
        uint2 o; o.x = pack2bf(v.x, v.y); o.y = pack2bf(v.z, v.w);
        d[j] = o;
    }
}

// ---------------------------------------------------------------------------
// GEMM: C[M,N] = A[M,K] @ B[N,K]^T + bias.  BM=128, BK=32, BN template.
// T3-min 2-phase: LDS double-buffered, tile t+1 DMA'd during tile t compute,
// one __syncthreads per K-step.  3 blocks/CU.
// MODE 1: fp32 out.  MODE 2: QKV epilogue -> Q (scaled 1/8), K, Vt (V^T).
// ---------------------------------------------------------------------------
template<int BN, int MODE>
__global__ __launch_bounds__(256, 3)
void gemm_k2(const u16* __restrict__ A, const u16* __restrict__ Bbf,
             const u16* __restrict__ biasbf, void* __restrict__ Cptr,
             u16* __restrict__ Qo, u16* __restrict__ Ko, u16* __restrict__ Vto,
             int M, int Nn, int K)
{
    constexpr int NFR = BN / 32;
    __shared__ __align__(16) u16 Alds[2][128 * 32];
    __shared__ __align__(16) u16 Blds[2][BN * 32];
    const int tid = threadIdx.x;
    const int w = tid >> 6, lane = tid & 63, quad = lane >> 4, l16 = lane & 15;
    const int m0 = blockIdx.x * 128, n0 = blockIdx.y * BN;
    const int wm = w >> 1, wn = w & 1;
    const int rA4 = lane >> 2, c8b = (lane & 3) * 8;   // gl_lds16: 4 lanes/row

    f32x4 acc[4][NFR] = {};

#define GSTAGE(k0_, bi_) do {                                                  \
    _Pragma("unroll")                                                          \
    for (int q = 0; q < 2; ++q) {                                              \
        int row0 = w * 32 + q * 16;                                            \
        gl_lds16(&A[(size_t)(m0 + row0 + rA4) * K + (k0_) + c8b],              \
                 &Alds[bi_][row0 * 32]);                                       \
    }                                                                          \
    _Pragma("unroll")                                                          \
    for (int q = 0; q < BN / 64; ++q) {                                        \
        int row0 = w * (BN / 4) + q * 16;                                      \
        gl_lds16(&Bbf[(size_t)(n0 + row0 + rA4) * K + (k0_) + c8b],            \
                 &Blds[bi_][row0 * 32]);                                       \
    }                                                                          \
} while (0)

    const int NT = K >> 5;
    GSTAGE(0, 0);
    for (int t = 0; t < NT; ++t) {
        const int cur = t & 1;
        __syncthreads();   // vmcnt(0) drain: tile t visible; buf cur^1 reads done
        if (t + 1 < NT) GSTAGE((t + 1) << 5, cur ^ 1);

        bf16x8 af[4], bfr[NFR];
#pragma unroll
        for (int mi = 0; mi < 4; ++mi)
            af[mi] = *(const bf16x8*)&Alds[cur][(wm * 64 + mi * 16 + l16) * 32 + quad * 8];
#pragma unroll
        for (int ni = 0; ni < NFR; ++ni)
            bfr[ni] = *(const bf16x8*)&Blds[cur][(wn * (BN / 2) + ni * 16 + l16) * 32 + quad * 8];
#pragma unroll
        for (int mi = 0; mi < 4; ++mi)
#pragma unroll
            for (int ni = 0; ni < NFR; ++ni)
                acc[mi][ni] = __builtin_amdgcn_mfma_f32_16x16x32_bf16(
                    af[mi], bfr[ni], acc[mi][ni], 0, 0, 0);
    }
#undef GSTAGE

    // epilogue: within 16x16 tile, row = quad*4+i, col = l16 (m89-verified)
#pragma unroll
    for (int mi = 0; mi < 4; ++mi) {
        int row_b = m0 + wm * 64 + mi * 16 + quad * 4;
#pragma unroll
        for (int ni = 0; ni < NFR; ++ni) {
            int col = n0 + wn * (BN / 2) + ni * 16 + l16;
            float bv = bf2f(biasbf[col]);
            if constexpr (MODE == 1) {
#pragma unroll
                for (int i = 0; i < 4; ++i)
                    ((float*)Cptr)[(size_t)(row_b + i) * Nn + col] = acc[mi][ni][i] + bv;
            } else {
                if (col < 1024) {            // Q, pre-scaled by 1/sqrt(D)
#pragma unroll
                    for (int i = 0; i < 4; ++i)
                        Qo[(size_t)(row_b + i) * 1024 + col] =
                            f2bf((acc[mi][ni][i] + bv) * 0.125f);
                } else if (col < 2048) {     // K
#pragma unroll
                    for (int i = 0; i < 4; ++i)
                        Ko[(size_t)(row_b + i) * 1024 + (col - 1024)] =
                            f2bf(acc[mi][ni][i] + bv);
                } else {                     // V -> Vt [b][h][d][s], pack 4 s
                    int d = col - 2048, hh = d >> 6, dd = d & 63;
                    int b = row_b >> 11, s = row_b & 2047;
                    u16 t0 = f2bf(acc[mi][ni][0] + bv), t1 = f2bf(acc[mi][ni][1] + bv);
                    u16 t2 = f2bf(acc[mi][ni][2] + bv), t3 = f2bf(acc[mi][ni][3] + bv);
                    uint2 pk; pk.x = (u32)t0 | ((u32)t1 << 16);
                    pk.y = (u32)t2 | ((u32)t3 << 16);
                    *(uint2*)&Vto[((size_t)((b * 16 + hh) * 64 + dd)) * 2048 + s] = pk;
                }
            }
        }
    }
}

// ---------------------------------------------------------------------------
// Causal flash attention v8 = v5 (proven-best geometry: 512 blocks x 4
// waves, uniform 33 tiles, 8 waves/CU, swapped QK^T + identity P repack,
// K staged via DMA with pi+XOR swizzle folded into global src) with ONE
// change: V is read DIRECTLY from global (Vlds deleted).  Rationale
// (v6/v7 evidence): with XCD affinity the head's K/V live in its 4MB L2
// (FETCH 12MB), and all 4 waves read the same 8KB V-tile -> L1 dedup.
// Guide Common-mistake #7: don't LDS-stage cache-resident data.  Halves
// LDS-pipe occupancy (the v5 bottleneck), halves DMA, LDS 32->16KB.
// V fragment = 16B chunks of Vt rows; 4 quads/row share a 64B line
// (coalesced); loads issue at tile top, latency hides under QK^T+exp.
// ---------------------------------------------------------------------------
__global__ __launch_bounds__(256, 2)
void attn_v8(const u16* __restrict__ Q, const u16* __restrict__ Kb,
             const u16* __restrict__ Vt, u16* __restrict__ attn_out) {
    // bid = (g&7) + 8*((g>>3) + 4*pr), g = h + 16*b  (bijective on [0,512))
    const int bid = blockIdx.x;
    const int r8 = bid & 7, qq = bid >> 3;
    const int pr = qq >> 2, g = (qq & 3) * 8 + r8;
    const int h = g & 15, b = g >> 4;
    const int tid = threadIdx.x;
    const int w = tid >> 6, lane = tid & 63, quad = lane >> 4, l16 = lane & 15;
    __shared__ __align__(16) u16 Klds[2][64 * 64];

    // K staging geometry: wave w DMAs stripes {2w, 2w+1}.
    // stripe s = 1KB = rows s*8..s*8+7; lane covers (row s*8+sl, chunk cch).
    const int sl = lane >> 3, cch = lane & 7;
    const int rho0 = (2 * w) * 8 + sl, rho1 = (2 * w + 1) * 8 + sl;
    const int gcs = (cch ^ sl) * 8;          // XOR swizzle (row&7 == sl)
    const int kg0 = ginv(rho0), kg1 = ginv(rho1);   // K global row (pi^-1)
    const int ls0 = (2 * w) * 512, ls1 = (2 * w + 1) * 512;
    // read-side swizzled chunk offsets (u16 units)
    const int xk0 = (quad ^ (l16 & 7)) * 8;
    const int xk1 = ((quad + 4) ^ (l16 & 7)) * 8;

    for (int half = 0; half < 2; ++half) {
        const int qt = half ? pr : (31 - pr);        // uniform 33 iters/block
        const int q0 = qt * 64;
        const int T = qt + 1;

        const u16* Qb = Q  + (size_t)(b * SS + q0) * 1024 + h * 64;
        const u16* Kg = Kb + (size_t)(b * SS) * 1024 + h * 64;
        const u16* Vg = Vt + (size_t)((b * 16 + h) * 64) * 2048;

#define STAGE_T(kv0_, bi_) do {                                               \
        gl_lds16(&Kg[(size_t)((kv0_) + kg0) * 1024 + gcs], &Klds[bi_][ls0]);  \
        gl_lds16(&Kg[(size_t)((kv0_) + kg1) * 1024 + gcs], &Klds[bi_][ls1]);  \
    } while (0)

        bf16x8 qf0 = *(const bf16x8*)&Qb[(size_t)(w * 16 + l16) * 1024 + quad * 8];
        bf16x8 qf1 = *(const bf16x8*)&Qb[(size_t)(w * 16 + l16) * 1024 + 32 + quad * 8];

        f32x4 oacc[4] = {};
        float lp = 0.f;

        __syncthreads();          // prior half's reads of buf0 done
        STAGE_T(0, 0);

        for (int t = 0; t < T; ++t) {
            const int cur = t & 1;
            __syncthreads();   // vmcnt drained: tile t staged; buf cur^1 reads done
            if (t + 1 < T) STAGE_T((t + 1) * 64, cur ^ 1);
            const int kv0 = t * 64;
            // ---- V fragments direct from global (L1/L2-resident) ----
            bf16x8 vf[4][2];
#pragma unroll
            for (int ni = 0; ni < 4; ++ni) {
                const u16* vr = &Vg[(size_t)(ni * 16 + l16) * 2048 + kv0];
                vf[ni][0] = *(const bf16x8*)&vr[quad * 8];
                vf[ni][1] = *(const bf16x8*)&vr[32 + quad * 8];
            }
            const u16* Kc = Klds[cur];
            // ---- S^T = K Q^T : 64 kv (rows, pi-permuted) x 16 q (cols) ----
            f32x4 sacc[4] = {};
#pragma unroll
            for (int ni = 0; ni < 4; ++ni) {
                const int rb = (ni * 16 + l16) * 64;
                bf16x8 kf0 = *(const bf16x8*)&Kc[rb + xk0];
                bf16x8 kf1 = *(const bf16x8*)&Kc[rb + xk1];
                sacc[ni] = __builtin_amdgcn_mfma_f32_16x16x32_bf16(kf0, qf0, sacc[ni], 0, 0, 0);
                sacc[ni] = __builtin_amdgcn_mfma_f32_16x16x32_bf16(kf1, qf1, sacc[ni], 0, 0, 0);
            }
            // ---- P = exp(S): in-register, packed; mask only diagonal tile ----
            u32 pk[4][2];
            if (t + 1 < T) {                 // interior: kv < q0 <= q, no mask
#pragma unroll
                for (int ni = 0; ni < 4; ++ni) {
                    float p0 = __expf(sacc[ni][0]), p1 = __expf(sacc[ni][1]);
                    float p2 = __expf(sacc[ni][2]), p3 = __expf(sacc[ni][3]);
                    lp += (p0 + p1) + (p2 + p3);
                    pk[ni][0] = pack2bf(p0, p1);
                    pk[ni][1] = pack2bf(p2, p3);
                }
            } else {                         // diagonal: keep kv-pos <= w*16+l16
                const int thr = w * 16 + l16;
#pragma unroll
                for (int ni = 0; ni < 4; ++ni) {
                    const int pb = 32 * (ni >> 1) + 8 * quad + 4 * (ni & 1);
                    float pv[4];
#pragma unroll
                    for (int i = 0; i < 4; ++i) {
                        float e = __expf(sacc[ni][i]);
                        pv[i] = (pb + i <= thr) ? e : 0.f;
                    }
                    lp += (pv[0] + pv[1]) + (pv[2] + pv[3]);
                    pk[ni][0] = pack2bf(pv[0], pv[1]);
                    pk[ni][1] = pack2bf(pv[2], pv[3]);
                }
            }
            // P A-fragment = identity repack (thanks to K row permutation)
            union { u32 u[4]; bf16x8 v; } pf0, pf1;
            pf0.u[0] = pk[0][0]; pf0.u[1] = pk[0][1];
            pf0.u[2] = pk[1][0]; pf0.u[3] = pk[1][1];
            pf1.u[0] = pk[2][0]; pf1.u[1] = pk[2][1];
            pf1.u[2] = pk[3][0]; pf1.u[3] = pk[3][1];
            // ---- O += P V ----
#pragma unroll
            for (int ni = 0; ni < 4; ++ni) {
                oacc[ni] = __builtin_amdgcn_mfma_f32_16x16x32_bf16(pf0.v, vf[ni][0], oacc[ni], 0, 0, 0);
                oacc[ni] = __builtin_amdgcn_mfma_f32_16x16x32_bf16(pf1.v, vf[ni][1], oacc[ni], 0, 0, 0);
            }
        }

        // ---- l: lane sum done; butterfly over quads; redistribute to rows ----
        lp += __shfl_xor(lp, 16, 64);
        lp += __shfl_xor(lp, 32, 64);      // now lp = l[q=l16], uniform in quad
        float linv[4];
#pragma unroll
        for (int i = 0; i < 4; ++i)
            linv[i] = 1.0f / __shfl(lp, quad * 4 + i, 64);  // l for q=quad*4+i

        // ---- O write: lane owns rows quad*4+i, cols ni*16+l16 ----
        u16* ob = attn_out + (size_t)(b * SS + q0 + w * 16) * 1024 + h * 64;
#pragma unroll
        for (int ni = 0; ni < 4; ++ni)
#pragma unroll
            for (int i = 0; i < 4; ++i)
                ob[(size_t)(quad * 4 + i) * 1024 + ni * 16 + l16] =
                    f2bf(oacc[ni][i] * linv[i]);
#undef STAGE_T
    }
}

// ---------------------------------------------------------------------------
// Memory plan (ws = 32 MB proven + d_out as scratch):
//   d_out [0,8M)   hid_bf [4096][1024]   (dead once GEMM1 done; GEMM2
//                                          overwrites all 16MB at the end)
//   ws [0,6M)      w_in_bf               (dead after GEMM1)
//   ws [6M,+6KB)   b_in_bf               (dead after GEMM1)
//   ws [0,8M)      attn_ws (alias)       (written by attn, read by GEMM2)
//   ws [8M,16M)    Q  [4096][1024] bf16, pre-scaled  (dead after attn)
//   ws [8M,10M)    w_out_bf (alias, written after attn)
//   ws [10M,+2KB)  b_out_bf (alias)
//   ws [16M,24M)   K  [4096][1024] bf16
//   ws [24M,32M)   Vt [2][16][64][2048] bf16
// ---------------------------------------------------------------------------
extern "C" void kernel_launch(void* const* d_in, const int* in_sizes, int n_in,
                              void* d_out, int out_size, void* d_ws, size_t ws_size,
                              hipStream_t stream) {
    const float* hidden = (const float*)d_in[0];
    const float* w_in   = (const float*)d_in[1];
    const float* b_in   = (const float*)d_in[2];
    const float* w_out  = (const float*)d_in[3];
    const float* b_out  = (const float*)d_in[4];
    float* out = (float*)d_out;

    char* ws = (char*)d_ws;
    u16* hid_bf  = (u16*)d_out;                       // scratch in d_out
    u16* wi_bf   = (u16*)ws;
    u16* bi_bf   = (u16*)(ws + 6291456);
    u16* attn_ws = (u16*)ws;
    u16* Qbuf    = (u16*)(ws + 8388608);
    u16* wo_bf   = (u16*)(ws + 8388608);
    u16* bo_bf   = (u16*)(ws + 8388608 + 2097152);
    u16* Kbuf    = (u16*)(ws + 16777216);
    u16* Vtbuf   = (u16*)(ws + 25165824);

    cvt3bf<<<dim3(2048), dim3(256), 0, stream>>>(
        (const float4*)hidden, (uint2*)hid_bf, 1048576,
        (const float4*)w_in,   (uint2*)wi_bf,  786432,
        (const float4*)b_in,   (uint2*)bi_bf,  768);
    gemm_k2<128, 2><<<dim3(32, 24), dim3(256), 0, stream>>>(
        hid_bf, wi_bf, bi_bf, nullptr, Qbuf, Kbuf, Vtbuf, MM, H3, HH);
    attn_v8<<<dim3(512), dim3(256), 0, stream>>>(
        Qbuf, Kbuf, Vtbuf, attn_ws);
    cvt3bf<<<dim3(512), dim3(256), 0, stream>>>(
        (const float4*)w_out, (uint2*)wo_bf, 262144,
        (const float4*)b_out, (uint2*)bo_bf, 256,
        nullptr, nullptr, 0);
    gemm_k2<64, 1><<<dim3(32, 16), dim3(256), 0, stream>>>(
        attn_ws, wo_bf, bo_bf, out, nullptr, nullptr, nullptr, MM, HH, HH);
}

// Round 7
// 176.417 us; speedup vs baseline: 1.1491x; 1.1491x over previous
//
#include <hip/hip_runtime.h>
#include <hip/hip_bf16.h>

// Problem constants
#define BB 2
#define SS 2048
#define HH 1024
#define NH 16
#define DD 64
#define H3 3072
#define MM (BB*SS)   // 4096 rows

typedef unsigned short u16;
typedef unsigned int u32;
typedef __attribute__((ext_vector_type(8))) short bf16x8;
typedef __attribute__((ext_vector_type(4))) float f32x4;

__device__ __forceinline__ u16 f2bf(float f) {
    union { float f; u32 u; } v; v.f = f;
    u32 u = v.u;
    u += 0x7fffu + ((u >> 16) & 1u);   // RNE
    return (u16)(u >> 16);
}
__device__ __forceinline__ float bf2f(u16 h) {
    union { u32 u; float f; } v; v.u = ((u32)h) << 16;
    return v.f;
}
__device__ __forceinline__ u32 pack2bf(float a, float b) {
    __hip_bfloat162 h = __float22bfloat162_rn(float2{a, b});
    u32 u; __builtin_memcpy(&u, &h, 4);
    return u;
}
// async global->LDS, 16B/lane; LDS dest = wave-uniform base + lane*16B.
__device__ __forceinline__ void gl_lds16(const void* g, void* l) {
    __builtin_amdgcn_global_load_lds(
        (const __attribute__((address_space(1))) u32*)g,
        (__attribute__((address_space(3))) u32*)l, 16, 0, 0);
}
// inverse of the K row bit-permutation Rp (g -> R): R4=g2 R3=g4 R2=g3, rest id.
// ginv(R): g = (R5,R3,R2,R4,R1,R0).  Verified: ginv(Rp(g)) == g.
__device__ __forceinline__ int ginv(int R) {
    return (R & 35) | ((R & 8) << 1) | ((R & 4) << 1) | ((R & 16) >> 2);
}

// ---------------------------------------------------------------------------
// fp32 -> bf16 bulk convert, three buffers per launch
// ---------------------------------------------------------------------------
__global__ void cvt3bf(const float4* __restrict__ s0, uint2* __restrict__ d0, int n0,
                       const float4* __restrict__ s1, uint2* __restrict__ d1, int n1,
                       const float4* __restrict__ s2, uint2* __restrict__ d2, int n2) {
    int i = blockIdx.x * blockDim.x + threadIdx.x;
    const int tot = n0 + n1 + n2;
    for (; i < tot; i += gridDim.x * blockDim.x) {
        const float4* s; uint2* d; int j;
        if (i < n0)            { s = s0; d = d0; j = i; }
        else if (i < n0 + n1)  { s = s1; d = d1; j = i - n0; }
        else                   { s = s2; d = d2; j = i - n0 - n1; }
        float4 v = s[j];
        uint2 o; o.x = pack2bf(v.x, v.y); o.y = pack2bf(v.z, v.w);
        d[j] = o;
    }
}

// ---------------------------------------------------------------------------
// GEMM: C[M,N] = A[M,K] @ B[N,K]^T + bias.  BM=128, BK=32, BN template.
// T3-min 2-phase: LDS double-buffered, tile t+1 DMA'd during tile t compute,
// one __syncthreads per K-step.  3 blocks/CU.
// T1 XCD chunk swizzle: nwg%8==0 (768/512); XCD k gets a contiguous run of
// tile indices -> its B-panel footprint is L2-resident (<=768KB vs 6MB).
// MODE 1: fp32 out.  MODE 2: QKV epilogue -> Q (scaled 1/8), K, Vt (V^T).
// ---------------------------------------------------------------------------
template<int BN, int MODE>
__global__ __launch_bounds__(256, 3)
void gemm_k2(const u16* __restrict__ A, const u16* __restrict__ Bbf,
             const u16* __restrict__ biasbf, void* __restrict__ Cptr,
             u16* __restrict__ Qo, u16* __restrict__ Ko, u16* __restrict__ Vto,
             int M, int Nn, int K)
{
    constexpr int NFR = BN / 32;
    __shared__ __align__(16) u16 Alds[2][128 * 32];
    __shared__ __align__(16) u16 Blds[2][BN * 32];
    const int tid = threadIdx.x;
    const int w = tid >> 6, lane = tid & 63, quad = lane >> 4, l16 = lane & 15;
    // XCD chunk swizzle (bijective; requires nwg % 8 == 0, true for both uses)
    const int gx = gridDim.x, nwg = gx * gridDim.y;
    const int f = blockIdx.y * gx + blockIdx.x;
    const int wg = (f & 7) * (nwg >> 3) + (f >> 3);
    const int m0 = (wg % gx) * 128, n0 = (wg / gx) * BN;
    const int wm = w >> 1, wn = w & 1;
    const int rA4 = lane >> 2, c8b = (lane & 3) * 8;   // gl_lds16: 4 lanes/row

    f32x4 acc[4][NFR] = {};

#define GSTAGE(k0_, bi_) do {                                                  \
    _Pragma("unroll")                                                          \
    for (int q = 0; q < 2; ++q) {                                              \
        int row0 = w * 32 + q * 16;                                            \
        gl_lds16(&A[(size_t)(m0 + row0 + rA4) * K + (k0_) + c8b],              \
                 &Alds[bi_][row0 * 32]);                                       \
    }                                                                          \
    _Pragma("unroll")                                                          \
    for (int q = 0; q < BN / 64; ++q) {                                        \
        int row0 = w * (BN / 4) + q * 16;                                      \
        gl_lds16(&Bbf[(size_t)(n0 + row0 + rA4) * K + (k0_) + c8b],            \
                 &Blds[bi_][row0 * 32]);                                       \
    }                                                                          \
} while (0)

    const int NT = K >> 5;
    GSTAGE(0, 0);
    for (int t = 0; t < NT; ++t) {
        const int cur = t & 1;
        __syncthreads();   // vmcnt(0) drain: tile t visible; buf cur^1 reads done
        if (t + 1 < NT) GSTAGE((t + 1) << 5, cur ^ 1);

        bf16x8 af[4], bfr[NFR];
#pragma unroll
        for (int mi = 0; mi < 4; ++mi)
            af[mi] = *(const bf16x8*)&Alds[cur][(wm * 64 + mi * 16 + l16) * 32 + quad * 8];
#pragma unroll
        for (int ni = 0; ni < NFR; ++ni)
            bfr[ni] = *(const bf16x8*)&Blds[cur][(wn * (BN / 2) + ni * 16 + l16) * 32 + quad * 8];
#pragma unroll
        for (int mi = 0; mi < 4; ++mi)
#pragma unroll
            for (int ni = 0; ni < NFR; ++ni)
                acc[mi][ni] = __builtin_amdgcn_mfma_f32_16x16x32_bf16(
                    af[mi], bfr[ni], acc[mi][ni], 0, 0, 0);
    }
#undef GSTAGE

    // epilogue: within 16x16 tile, row = quad*4+i, col = l16 (m89-verified)
#pragma unroll
    for (int mi = 0; mi < 4; ++mi) {
        int row_b = m0 + wm * 64 + mi * 16 + quad * 4;
#pragma unroll
        for (int ni = 0; ni < NFR; ++ni) {
            int col = n0 + wn * (BN / 2) + ni * 16 + l16;
            float bv = bf2f(biasbf[col]);
            if constexpr (MODE == 1) {
#pragma unroll
                for (int i = 0; i < 4; ++i)
                    ((float*)Cptr)[(size_t)(row_b + i) * Nn + col] = acc[mi][ni][i] + bv;
            } else {
                if (col < 1024) {            // Q, pre-scaled by 1/sqrt(D)
#pragma unroll
                    for (int i = 0; i < 4; ++i)
                        Qo[(size_t)(row_b + i) * 1024 + col] =
                            f2bf((acc[mi][ni][i] + bv) * 0.125f);
                } else if (col < 2048) {     // K
#pragma unroll
                    for (int i = 0; i < 4; ++i)
                        Ko[(size_t)(row_b + i) * 1024 + (col - 1024)] =
                            f2bf(acc[mi][ni][i] + bv);
                } else {                     // V -> Vt [b][h][d][s], pack 4 s
                    int d = col - 2048, hh = d >> 6, dd = d & 63;
                    int b = row_b >> 11, s = row_b & 2047;
                    u16 t0 = f2bf(acc[mi][ni][0] + bv), t1 = f2bf(acc[mi][ni][1] + bv);
                    u16 t2 = f2bf(acc[mi][ni][2] + bv), t3 = f2bf(acc[mi][ni][3] + bv);
                    uint2 pk; pk.x = (u32)t0 | ((u32)t1 << 16);
                    pk.y = (u32)t2 | ((u32)t3 << 16);
                    *(uint2*)&Vto[((size_t)((b * 16 + hh) * 64 + dd)) * 2048 + s] = pk;
                }
            }
        }
    }
}

// ---------------------------------------------------------------------------
// Causal flash attention v9 = v5 (proven best: 512 blocks x 4 waves,
// uniform 33 tiles, 8 waves/CU, swapped QK^T + identity P repack, K AND V
// double-buffered in LDS via DMA with pi+XOR swizzle folded into the global
// source, conflict-free reads, XCD-affine grid) + ONE tweak: the 8 V
// ds_read_b128 are HOISTED to the tile top (issued with the K reads) so
// their LDS latency hides under the 16 QK^T MFMAs + exp chain instead of
// stalling right before the PV MFMAs.  No sync/layout changes.
// ---------------------------------------------------------------------------
__global__ __launch_bounds__(256, 2)
void attn_v9(const u16* __restrict__ Q, const u16* __restrict__ Kb,
             const u16* __restrict__ Vt, u16* __restrict__ attn_out) {
    // bid = (g&7) + 8*((g>>3) + 4*pr), g = h + 16*b  (bijective on [0,512))
    const int bid = blockIdx.x;
    const int r8 = bid & 7, qq = bid >> 3;
    const int pr = qq >> 2, g = (qq & 3) * 8 + r8;
    const int h = g & 15, b = g >> 4;
    const int tid = threadIdx.x;
    const int w = tid >> 6, lane = tid & 63, quad = lane >> 4, l16 = lane & 15;
    __shared__ __align__(16) u16 Klds[2][64 * 64];
    __shared__ __align__(16) u16 Vlds[2][64 * 64];

    // staging geometry: wave w DMAs stripes {2w, 2w+1} of K and V.
    // stripe s = 1KB = rows s*8..s*8+7; lane covers (row s*8+sl, chunk cch).
    const int sl = lane >> 3, cch = lane & 7;
    const int rho0 = (2 * w) * 8 + sl, rho1 = (2 * w + 1) * 8 + sl;
    const int gcs = (cch ^ sl) * 8;          // XOR swizzle (row&7 == sl)
    const int kg0 = ginv(rho0), kg1 = ginv(rho1);   // K global row (pi^-1)
    const int ls0 = (2 * w) * 512, ls1 = (2 * w + 1) * 512;
    // read-side swizzled chunk offsets (u16 units)
    const int xk0 = (quad ^ (l16 & 7)) * 8;
    const int xk1 = ((quad + 4) ^ (l16 & 7)) * 8;

    for (int half = 0; half < 2; ++half) {
        const int qt = half ? pr : (31 - pr);        // uniform 33 iters/block
        const int q0 = qt * 64;
        const int T = qt + 1;

        const u16* Qb = Q  + (size_t)(b * SS + q0) * 1024 + h * 64;
        const u16* Kg = Kb + (size_t)(b * SS) * 1024 + h * 64;
        const u16* Vg = Vt + (size_t)((b * 16 + h) * 64) * 2048;

#define STAGE_T(kv0_, bi_) do {                                               \
        gl_lds16(&Kg[(size_t)((kv0_) + kg0) * 1024 + gcs], &Klds[bi_][ls0]);  \
        gl_lds16(&Kg[(size_t)((kv0_) + kg1) * 1024 + gcs], &Klds[bi_][ls1]);  \
        gl_lds16(&Vg[(size_t)rho0 * 2048 + (kv0_) + gcs], &Vlds[bi_][ls0]);   \
        gl_lds16(&Vg[(size_t)rho1 * 2048 + (kv0_) + gcs], &Vlds[bi_][ls1]);   \
    } while (0)

        bf16x8 qf0 = *(const bf16x8*)&Qb[(size_t)(w * 16 + l16) * 1024 + quad * 8];
        bf16x8 qf1 = *(const bf16x8*)&Qb[(size_t)(w * 16 + l16) * 1024 + 32 + quad * 8];

        f32x4 oacc[4] = {};
        float lp = 0.f;

        __syncthreads();          // prior half's reads of buf0 done
        STAGE_T(0, 0);

        for (int t = 0; t < T; ++t) {
            const int cur = t & 1;
            __syncthreads();   // vmcnt drained: tile t staged; buf cur^1 reads done
            if (t + 1 < T) STAGE_T((t + 1) * 64, cur ^ 1);
            const u16* Kc = Klds[cur];
            const u16* Vc = Vlds[cur];
            // ---- hoisted V fragment reads: latency hides under QK^T+exp ----
            bf16x8 vf[4][2];
#pragma unroll
            for (int ni = 0; ni < 4; ++ni) {
                const int rb = (ni * 16 + l16) * 64;
                vf[ni][0] = *(const bf16x8*)&Vc[rb + xk0];
                vf[ni][1] = *(const bf16x8*)&Vc[rb + xk1];
            }
            // ---- S^T = K Q^T : 64 kv (rows, pi-permuted) x 16 q (cols) ----
            f32x4 sacc[4] = {};
#pragma unroll
            for (int ni = 0; ni < 4; ++ni) {
                const int rb = (ni * 16 + l16) * 64;
                bf16x8 kf0 = *(const bf16x8*)&Kc[rb + xk0];
                bf16x8 kf1 = *(const bf16x8*)&Kc[rb + xk1];
                sacc[ni] = __builtin_amdgcn_mfma_f32_16x16x32_bf16(kf0, qf0, sacc[ni], 0, 0, 0);
                sacc[ni] = __builtin_amdgcn_mfma_f32_16x16x32_bf16(kf1, qf1, sacc[ni], 0, 0, 0);
            }
            // ---- P = exp(S): in-register, packed; mask only diagonal tile ----
            u32 pk[4][2];
            if (t + 1 < T) {                 // interior: kv < q0 <= q, no mask
#pragma unroll
                for (int ni = 0; ni < 4; ++ni) {
                    float p0 = __expf(sacc[ni][0]), p1 = __expf(sacc[ni][1]);
                    float p2 = __expf(sacc[ni][2]), p3 = __expf(sacc[ni][3]);
                    lp += (p0 + p1) + (p2 + p3);
                    pk[ni][0] = pack2bf(p0, p1);
                    pk[ni][1] = pack2bf(p2, p3);
                }
            } else {                         // diagonal: keep kv-pos <= w*16+l16
                const int thr = w * 16 + l16;
#pragma unroll
                for (int ni = 0; ni < 4; ++ni) {
                    const int pb = 32 * (ni >> 1) + 8 * quad + 4 * (ni & 1);
                    float pv[4];
#pragma unroll
                    for (int i = 0; i < 4; ++i) {
                        float e = __expf(sacc[ni][i]);
                        pv[i] = (pb + i <= thr) ? e : 0.f;
                    }
                    lp += (pv[0] + pv[1]) + (pv[2] + pv[3]);
                    pk[ni][0] = pack2bf(pv[0], pv[1]);
                    pk[ni][1] = pack2bf(pv[2], pv[3]);
                }
            }
            // P A-fragment = identity repack (thanks to K row permutation)
            union { u32 u[4]; bf16x8 v; } pf0, pf1;
            pf0.u[0] = pk[0][0]; pf0.u[1] = pk[0][1];
            pf0.u[2] = pk[1][0]; pf0.u[3] = pk[1][1];
            pf1.u[0] = pk[2][0]; pf1.u[1] = pk[2][1];
            pf1.u[2] = pk[3][0]; pf1.u[3] = pk[3][1];
            // ---- O += P V ----
#pragma unroll
            for (int ni = 0; ni < 4; ++ni) {
                oacc[ni] = __builtin_amdgcn_mfma_f32_16x16x32_bf16(pf0.v, vf[ni][0], oacc[ni], 0, 0, 0);
                oacc[ni] = __builtin_amdgcn_mfma_f32_16x16x32_bf16(pf1.v, vf[ni][1], oacc[ni], 0, 0, 0);
            }
        }

        // ---- l: lane sum done; butterfly over quads; redistribute to rows ----
        lp += __shfl_xor(lp, 16, 64);
        lp += __shfl_xor(lp, 32, 64);      // now lp = l[q=l16], uniform in quad
        float linv[4];
#pragma unroll
        for (int i = 0; i < 4; ++i)
            linv[i] = 1.0f / __shfl(lp, quad * 4 + i, 64);  // l for q=quad*4+i

        // ---- O write: lane owns rows quad*4+i, cols ni*16+l16 ----
        u16* ob = attn_out + (size_t)(b * SS + q0 + w * 16) * 1024 + h * 64;
#pragma unroll
        for (int ni = 0; ni < 4; ++ni)
#pragma unroll
            for (int i = 0; i < 4; ++i)
                ob[(size_t)(quad * 4 + i) * 1024 + ni * 16 + l16] =
                    f2bf(oacc[ni][i] * linv[i]);
#undef STAGE_T
    }
}

// ---------------------------------------------------------------------------
// Memory plan (ws = 32 MB proven + d_out as scratch):
//   d_out [0,8M)   hid_bf [4096][1024]   (dead once GEMM1 done; GEMM2
//                                          overwrites all 16MB at the end)
//   ws [0,6M)      w_in_bf               (dead after GEMM1)
//   ws [6M,+6KB)   b_in_bf               (dead after GEMM1)
//   ws [0,8M)      attn_ws (alias)       (written by attn, read by GEMM2)
//   ws [8M,16M)    Q  [4096][1024] bf16, pre-scaled  (dead after attn)
//   ws [8M,10M)    w_out_bf (alias, written after attn)
//   ws [10M,+2KB)  b_out_bf (alias)
//   ws [16M,24M)   K  [4096][1024] bf16
//   ws [24M,32M)   Vt [2][16][64][2048] bf16
// ---------------------------------------------------------------------------
extern "C" void kernel_launch(void* const* d_in, const int* in_sizes, int n_in,
                              void* d_out, int out_size, void* d_ws, size_t ws_size,
                              hipStream_t stream) {
    const float* hidden = (const float*)d_in[0];
    const float* w_in   = (const float*)d_in[1];
    const float* b_in   = (const float*)d_in[2];
    const float* w_out  = (const float*)d_in[3];
    const float* b_out  = (const float*)d_in[4];
    float* out = (float*)d_out;

    char* ws = (char*)d_ws;
    u16* hid_bf  = (u16*)d_out;                       // scratch in d_out
    u16* wi_bf   = (u16*)ws;
    u16* bi_bf   = (u16*)(ws + 6291456);
    u16* attn_ws = (u16*)ws;
    u16* Qbuf    = (u16*)(ws + 8388608);
    u16* wo_bf   = (u16*)(ws + 8388608);
    u16* bo_bf   = (u16*)(ws + 8388608 + 2097152);
    u16* Kbuf    = (u16*)(ws + 16777216);
    u16* Vtbuf   = (u16*)(ws + 25165824);

    cvt3bf<<<dim3(2048), dim3(256), 0, stream>>>(
        (const float4*)hidden, (uint2*)hid_bf, 1048576,
        (const float4*)w_in,   (uint2*)wi_bf,  786432,
        (const float4*)b_in,   (uint2*)bi_bf,  768);
    gemm_k2<128, 2><<<dim3(32, 24), dim3(256), 0, stream>>>(
        hid_bf, wi_bf, bi_bf, nullptr, Qbuf, Kbuf, Vtbuf, MM, H3, HH);
    attn_v9<<<dim3(512), dim3(256), 0, stream>>>(
        Qbuf, Kbuf, Vtbuf, attn_ws);
    cvt3bf<<<dim3(512), dim3(256), 0, stream>>>(
        (const float4*)w_out, (uint2*)wo_bf, 262144,
        (const float4*)b_out, (uint2*)bo_bf, 256,
        nullptr, nullptr, 0);
    gemm_k2<64, 1><<<dim3(32, 16), dim3(256), 0, stream>>>(
        attn_ws, wo_bf, bo_bf, out, nullptr, nullptr, nullptr, MM, HH, HH);
}

// Round 9
// 176.358 us; speedup vs baseline: 1.1494x; 1.0003x over previous
//
#include <hip/hip_runtime.h>
#include <hip/hip_bf16.h>

// Problem constants
#define BB 2
#define SS 2048
#define HH 1024
#define NH 16
#define DD 64
#define H3 3072
#define MM (BB*SS)   // 4096 rows

typedef unsigned short u16;
typedef unsigned int u32;
typedef __attribute__((ext_vector_type(8))) short bf16x8;
typedef __attribute__((ext_vector_type(4))) float f32x4;

__device__ __forceinline__ u16 f2bf(float f) {
    union { float f; u32 u; } v; v.f = f;
    u32 u = v.u;
    u += 0x7fffu + ((u >> 16) & 1u);   // RNE
    return (u16)(u >> 16);
}
__device__ __forceinline__ float bf2f(u16 h) {
    union { u32 u; float f; } v; v.u = ((u32)h) << 16;
    return v.f;
}
__device__ __forceinline__ u32 pack2bf(float a, float b) {
    __hip_bfloat162 h = __float22bfloat162_rn(float2{a, b});
    u32 u; __builtin_memcpy(&u, &h, 4);
    return u;
}
// 2^x via the native transcendental unit (v_exp_f32 computes 2^S0).
__device__ __forceinline__ float exp2v(float x) {
    float r;
    asm volatile("v_exp_f32 %0, %1" : "=v"(r) : "v"(x));
    return r;
}
// async global->LDS, 16B/lane; LDS dest = wave-uniform base + lane*16B.
__device__ __forceinline__ void gl_lds16(const void* g, void* l) {
    __builtin_amdgcn_global_load_lds(
        (const __attribute__((address_space(1))) u32*)g,
        (__attribute__((address_space(3))) u32*)l, 16, 0, 0);
}
// inverse of the K row bit-permutation Rp (g -> R): R4=g2 R3=g4 R2=g3, rest id.
// ginv(R): g = (R5,R3,R2,R4,R1,R0).  Verified: ginv(Rp(g)) == g.
__device__ __forceinline__ int ginv(int R) {
    return (R & 35) | ((R & 8) << 1) | ((R & 4) << 1) | ((R & 16) >> 2);
}

// ---------------------------------------------------------------------------
// fp32 -> bf16 bulk convert, three buffers per launch
// ---------------------------------------------------------------------------
__global__ void cvt3bf(const float4* __restrict__ s0, uint2* __restrict__ d0, int n0,
                       const float4* __restrict__ s1, uint2* __restrict__ d1, int n1,
                       const float4* __restrict__ s2, uint2* __restrict__ d2, int n2) {
    int i = blockIdx.x * blockDim.x + threadIdx.x;
    const int tot = n0 + n1 + n2;
    for (; i < tot; i += gridDim.x * blockDim.x) {
        const float4* s; uint2* d; int j;
        if (i < n0)            { s = s0; d = d0; j = i; }
        else if (i < n0 + n1)  { s = s1; d = d1; j = i - n0; }
        else                   { s = s2; d = d2; j = i - n0 - n1; }
        float4 v = s[j];
        uint2 o; o.x = pack2bf(v.x, v.y); o.y = pack2bf(v.z, v.w);
        d[j] = o;
    }
}

// ---------------------------------------------------------------------------
// GEMM: C[M,N] = A[M,K] @ B[N,K]^T + bias.  BM=128, BK=32, BN template.
// T3-min 2-phase: LDS double-buffered, tile t+1 DMA'd during tile t compute,
// one __syncthreads per K-step.  3 blocks/CU.
// T1 XCD chunk swizzle: nwg%8==0 (768/512); XCD k gets a contiguous run of
// tile indices -> its B-panel footprint is L2-resident (<=768KB vs 6MB).
// MODE 1: fp32 out.  MODE 2: QKV epilogue -> Q (scaled log2e/8), K, Vt (V^T).
// ---------------------------------------------------------------------------
template<int BN, int MODE>
__global__ __launch_bounds__(256, 3)
void gemm_k2(const u16* __restrict__ A, const u16* __restrict__ Bbf,
             const u16* __restrict__ biasbf, void* __restrict__ Cptr,
             u16* __restrict__ Qo, u16* __restrict__ Ko, u16* __restrict__ Vto,
             int M, int Nn, int K)
{
    constexpr int NFR = BN / 32;
    __shared__ __align__(16) u16 Alds[2][128 * 32];
    __shared__ __align__(16) u16 Blds[2][BN * 32];
    const int tid = threadIdx.x;
    const int w = tid >> 6, lane = tid & 63, quad = lane >> 4, l16 = lane & 15;
    // XCD chunk swizzle (bijective; requires nwg % 8 == 0, true for both uses)
    const int gx = gridDim.x, nwg = gx * gridDim.y;
    const int f = blockIdx.y * gx + blockIdx.x;
    const int wg = (f & 7) * (nwg >> 3) + (f >> 3);
    const int m0 = (wg % gx) * 128, n0 = (wg / gx) * BN;
    const int wm = w >> 1, wn = w & 1;
    const int rA4 = lane >> 2, c8b = (lane & 3) * 8;   // gl_lds16: 4 lanes/row

    f32x4 acc[4][NFR] = {};

#define GSTAGE(k0_, bi_) do {                                                  \
    _Pragma("unroll")                                                          \
    for (int q = 0; q < 2; ++q) {                                              \
        int row0 = w * 32 + q * 16;                                            \
        gl_lds16(&A[(size_t)(m0 + row0 + rA4) * K + (k0_) + c8b],              \
                 &Alds[bi_][row0 * 32]);                                       \
    }                                                                          \
    _Pragma("unroll")                                                          \
    for (int q = 0; q < BN / 64; ++q) {                                        \
        int row0 = w * (BN / 4) + q * 16;                                      \
        gl_lds16(&Bbf[(size_t)(n0 + row0 + rA4) * K + (k0_) + c8b],            \
                 &Blds[bi_][row0 * 32]);                                       \
    }                                                                          \
} while (0)

    const int NT = K >> 5;
    GSTAGE(0, 0);
    for (int t = 0; t < NT; ++t) {
        const int cur = t & 1;
        __syncthreads();   // vmcnt(0) drain: tile t visible; buf cur^1 reads done
        if (t + 1 < NT) GSTAGE((t + 1) << 5, cur ^ 1);

        bf16x8 af[4], bfr[NFR];
#pragma unroll
        for (int mi = 0; mi < 4; ++mi)
            af[mi] = *(const bf16x8*)&Alds[cur][(wm * 64 + mi * 16 + l16) * 32 + quad * 8];
#pragma unroll
        for (int ni = 0; ni < NFR; ++ni)
            bfr[ni] = *(const bf16x8*)&Blds[cur][(wn * (BN / 2) + ni * 16 + l16) * 32 + quad * 8];
#pragma unroll
        for (int mi = 0; mi < 4; ++mi)
#pragma unroll
            for (int ni = 0; ni < NFR; ++ni)
                acc[mi][ni] = __builtin_amdgcn_mfma_f32_16x16x32_bf16(
                    af[mi], bfr[ni], acc[mi][ni], 0, 0, 0);
    }
#undef GSTAGE

    // epilogue: within 16x16 tile, row = quad*4+i, col = l16 (m89-verified)
#pragma unroll
    for (int mi = 0; mi < 4; ++mi) {
        int row_b = m0 + wm * 64 + mi * 16 + quad * 4;
#pragma unroll
        for (int ni = 0; ni < NFR; ++ni) {
            int col = n0 + wn * (BN / 2) + ni * 16 + l16;
            float bv = bf2f(biasbf[col]);
            if constexpr (MODE == 1) {
#pragma unroll
                for (int i = 0; i < 4; ++i)
                    ((float*)Cptr)[(size_t)(row_b + i) * Nn + col] = acc[mi][ni][i] + bv;
            } else {
                if (col < 1024) {            // Q, pre-scaled by log2e/sqrt(D):
                                             // attn uses exp2 (v_exp_f32 is 2^x;
                                             // saves a VALU mul per score)
#pragma unroll
                    for (int i = 0; i < 4; ++i)
                        Qo[(size_t)(row_b + i) * 1024 + col] =
                            f2bf((acc[mi][ni][i] + bv) * 0.18033688f);
                } else if (col < 2048) {     // K
#pragma unroll
                    for (int i = 0; i < 4; ++i)
                        Ko[(size_t)(row_b + i) * 1024 + (col - 1024)] =
                            f2bf(acc[mi][ni][i] + bv);
                } else {                     // V -> Vt [b][h][d][s], pack 4 s
                    int d = col - 2048, hh = d >> 6, dd = d & 63;
                    int b = row_b >> 11, s = row_b & 2047;
                    u16 t0 = f2bf(acc[mi][ni][0] + bv), t1 = f2bf(acc[mi][ni][1] + bv);
                    u16 t2 = f2bf(acc[mi][ni][2] + bv), t3 = f2bf(acc[mi][ni][3] + bv);
                    uint2 pk; pk.x = (u32)t0 | ((u32)t1 << 16);
                    pk.y = (u32)t2 | ((u32)t3 << 16);
                    *(uint2*)&Vto[((size_t)((b * 16 + hh) * 64 + dd)) * 2048 + s] = pk;
                }
            }
        }
    }
}

// ---------------------------------------------------------------------------
// Causal flash attention v10 = v5 (proven best: 512 blocks x 4 waves,
// uniform 33 tiles, 8 waves/CU, swapped QK^T + identity P repack, K AND V
// double-buffered in LDS via DMA with pi+XOR swizzle folded into the global
// source, conflict-free reads, XCD-affine grid) + exp2 softmax: Q carries
// the log2e factor from gemm1, so P = exp2(S) with no per-score mul
// (exp2v = raw v_exp_f32 inline asm; __exp2f does not exist in HIP).
// ---------------------------------------------------------------------------
__global__ __launch_bounds__(256, 2)
void attn_v10(const u16* __restrict__ Q, const u16* __restrict__ Kb,
              const u16* __restrict__ Vt, u16* __restrict__ attn_out) {
    // bid = (g&7) + 8*((g>>3) + 4*pr), g = h + 16*b  (bijective on [0,512))
    const int bid = blockIdx.x;
    const int r8 = bid & 7, qq = bid >> 3;
    const int pr = qq >> 2, g = (qq & 3) * 8 + r8;
    const int h = g & 15, b = g >> 4;
    const int tid = threadIdx.x;
    const int w = tid >> 6, lane = tid & 63, quad = lane >> 4, l16 = lane & 15;
    __shared__ __align__(16) u16 Klds[2][64 * 64];
    __shared__ __align__(16) u16 Vlds[2][64 * 64];

    // staging geometry: wave w DMAs stripes {2w, 2w+1} of K and V.
    // stripe s = 1KB = rows s*8..s*8+7; lane covers (row s*8+sl, chunk cch).
    const int sl = lane >> 3, cch = lane & 7;
    const int rho0 = (2 * w) * 8 + sl, rho1 = (2 * w + 1) * 8 + sl;
    const int gcs = (cch ^ sl) * 8;          // XOR swizzle (row&7 == sl)
    const int kg0 = ginv(rho0), kg1 = ginv(rho1);   // K global row (pi^-1)
    const int ls0 = (2 * w) * 512, ls1 = (2 * w + 1) * 512;
    // read-side swizzled chunk offsets (u16 units)
    const int xk0 = (quad ^ (l16 & 7)) * 8;
    const int xk1 = ((quad + 4) ^ (l16 & 7)) * 8;

    for (int half = 0; half < 2; ++half) {
        const int qt = half ? pr : (31 - pr);        // uniform 33 iters/block
        const int q0 = qt * 64;
        const int T = qt + 1;

        const u16* Qb = Q  + (size_t)(b * SS + q0) * 1024 + h * 64;
        const u16* Kg = Kb + (size_t)(b * SS) * 1024 + h * 64;
        const u16* Vg = Vt + (size_t)((b * 16 + h) * 64) * 2048;

#define STAGE_T(kv0_, bi_) do {                                               \
        gl_lds16(&Kg[(size_t)((kv0_) + kg0) * 1024 + gcs], &Klds[bi_][ls0]);  \
        gl_lds16(&Kg[(size_t)((kv0_) + kg1) * 1024 + gcs], &Klds[bi_][ls1]);  \
        gl_lds16(&Vg[(size_t)rho0 * 2048 + (kv0_) + gcs], &Vlds[bi_][ls0]);   \
        gl_lds16(&Vg[(size_t)rho1 * 2048 + (kv0_) + gcs], &Vlds[bi_][ls1]);   \
    } while (0)

        bf16x8 qf0 = *(const bf16x8*)&Qb[(size_t)(w * 16 + l16) * 1024 + quad * 8];
        bf16x8 qf1 = *(const bf16x8*)&Qb[(size_t)(w * 16 + l16) * 1024 + 32 + quad * 8];

        f32x4 oacc[4] = {};
        float lp = 0.f;

        __syncthreads();          // prior half's reads of buf0 done
        STAGE_T(0, 0);

        for (int t = 0; t < T; ++t) {
            const int cur = t & 1;
            __syncthreads();   // vmcnt drained: tile t staged; buf cur^1 reads done
            if (t + 1 < T) STAGE_T((t + 1) * 64, cur ^ 1);
            const u16* Kc = Klds[cur];
            const u16* Vc = Vlds[cur];
            // ---- S^T = K Q^T : 64 kv (rows, pi-permuted) x 16 q (cols) ----
            f32x4 sacc[4] = {};
#pragma unroll
            for (int ni = 0; ni < 4; ++ni) {
                const int rb = (ni * 16 + l16) * 64;
                bf16x8 kf0 = *(const bf16x8*)&Kc[rb + xk0];
                bf16x8 kf1 = *(const bf16x8*)&Kc[rb + xk1];
                sacc[ni] = __builtin_amdgcn_mfma_f32_16x16x32_bf16(kf0, qf0, sacc[ni], 0, 0, 0);
                sacc[ni] = __builtin_amdgcn_mfma_f32_16x16x32_bf16(kf1, qf1, sacc[ni], 0, 0, 0);
            }
            // ---- P = exp2(S): in-register, packed; mask only diagonal tile ----
            u32 pk[4][2];
            if (t + 1 < T) {                 // interior: kv < q0 <= q, no mask
#pragma unroll
                for (int ni = 0; ni < 4; ++ni) {
                    float p0 = exp2v(sacc[ni][0]), p1 = exp2v(sacc[ni][1]);
                    float p2 = exp2v(sacc[ni][2]), p3 = exp2v(sacc[ni][3]);
                    lp += (p0 + p1) + (p2 + p3);
                    pk[ni][0] = pack2bf(p0, p1);
                    pk[ni][1] = pack2bf(p2, p3);
                }
            } else {                         // diagonal: keep kv-pos <= w*16+l16
                const int thr = w * 16 + l16;
#pragma unroll
                for (int ni = 0; ni < 4; ++ni) {
                    const int pb = 32 * (ni >> 1) + 8 * quad + 4 * (ni & 1);
                    float pv[4];
#pragma unroll
                    for (int i = 0; i < 4; ++i) {
                        float e = exp2v(sacc[ni][i]);
                        pv[i] = (pb + i <= thr) ? e : 0.f;
                    }
                    lp += (pv[0] + pv[1]) + (pv[2] + pv[3]);
                    pk[ni][0] = pack2bf(pv[0], pv[1]);
                    pk[ni][1] = pack2bf(pv[2], pv[3]);
                }
            }
            // P A-fragment = identity repack (thanks to K row permutation)
            union { u32 u[4]; bf16x8 v; } pf0, pf1;
            pf0.u[0] = pk[0][0]; pf0.u[1] = pk[0][1];
            pf0.u[2] = pk[1][0]; pf0.u[3] = pk[1][1];
            pf1.u[0] = pk[2][0]; pf1.u[1] = pk[2][1];
            pf1.u[2] = pk[3][0]; pf1.u[3] = pk[3][1];
            // ---- O += P V ----
#pragma unroll
            for (int ni = 0; ni < 4; ++ni) {
                const int rb = (ni * 16 + l16) * 64;
                bf16x8 vf0 = *(const bf16x8*)&Vc[rb + xk0];
                bf16x8 vf1 = *(const bf16x8*)&Vc[rb + xk1];
                oacc[ni] = __builtin_amdgcn_mfma_f32_16x16x32_bf16(pf0.v, vf0, oacc[ni], 0, 0, 0);
                oacc[ni] = __builtin_amdgcn_mfma_f32_16x16x32_bf16(pf1.v, vf1, oacc[ni], 0, 0, 0);
            }
        }

        // ---- l: lane sum done; butterfly over quads; redistribute to rows ----
        lp += __shfl_xor(lp, 16, 64);
        lp += __shfl_xor(lp, 32, 64);      // now lp = l[q=l16], uniform in quad
        float linv[4];
#pragma unroll
        for (int i = 0; i < 4; ++i)
            linv[i] = 1.0f / __shfl(lp, quad * 4 + i, 64);  // l for q=quad*4+i

        // ---- O write: lane owns rows quad*4+i, cols ni*16+l16 ----
        u16* ob = attn_out + (size_t)(b * SS + q0 + w * 16) * 1024 + h * 64;
#pragma unroll
        for (int ni = 0; ni < 4; ++ni)
#pragma unroll
            for (int i = 0; i < 4; ++i)
                ob[(size_t)(quad * 4 + i) * 1024 + ni * 16 + l16] =
                    f2bf(oacc[ni][i] * linv[i]);
#undef STAGE_T
    }
}

// ---------------------------------------------------------------------------
// Memory plan (ws = 32 MB proven + d_out as scratch):
//   d_out [0,8M)   hid_bf [4096][1024]   (dead once GEMM1 done; GEMM2
//                                          overwrites all 16MB at the end)
//   ws [0,6M)      w_in_bf               (dead after GEMM1)
//   ws [6M,+6KB)   b_in_bf               (dead after GEMM1)
//   ws [0,8M)      attn_ws (alias)       (written by attn, read by GEMM2)
//   ws [8M,16M)    Q  [4096][1024] bf16, pre-scaled  (dead after attn)
//   ws [8M,10M)    w_out_bf (alias, written after attn)
//   ws [10M,+2KB)  b_out_bf (alias)
//   ws [16M,24M)   K  [4096][1024] bf16
//   ws [24M,32M)   Vt [2][16][64][2048] bf16
// ---------------------------------------------------------------------------
extern "C" void kernel_launch(void* const* d_in, const int* in_sizes, int n_in,
                              void* d_out, int out_size, void* d_ws, size_t ws_size,
                              hipStream_t stream) {
    const float* hidden = (const float*)d_in[0];
    const float* w_in   = (const float*)d_in[1];
    const float* b_in   = (const float*)d_in[2];
    const float* w_out  = (const float*)d_in[3];
    const float* b_out  = (const float*)d_in[4];
    float* out = (float*)d_out;

    char* ws = (char*)d_ws;
    u16* hid_bf  = (u16*)d_out;                       // scratch in d_out
    u16* wi_bf   = (u16*)ws;
    u16* bi_bf   = (u16*)(ws + 6291456);
    u16* attn_ws = (u16*)ws;
    u16* Qbuf    = (u16*)(ws + 8388608);
    u16* wo_bf   = (u16*)(ws + 8388608);
    u16* bo_bf   = (u16*)(ws + 8388608 + 2097152);
    u16* Kbuf    = (u16*)(ws + 16777216);
    u16* Vtbuf   = (u16*)(ws + 25165824);

    cvt3bf<<<dim3(2048), dim3(256), 0, stream>>>(
        (const float4*)hidden, (uint2*)hid_bf, 1048576,
        (const float4*)w_in,   (uint2*)wi_bf,  786432,
        (const float4*)b_in,   (uint2*)bi_bf,  768);
    gemm_k2<128, 2><<<dim3(32, 24), dim3(256), 0, stream>>>(
        hid_bf, wi_bf, bi_bf, nullptr, Qbuf, Kbuf, Vtbuf, MM, H3, HH);
    attn_v10<<<dim3(512), dim3(256), 0, stream>>>(
        Qbuf, Kbuf, Vtbuf, attn_ws);
    cvt3bf<<<dim3(512), dim3(256), 0, stream>>>(
        (const float4*)w_out, (uint2*)wo_bf, 262144,
        (const float4*)b_out, (uint2*)bo_bf, 256,
        nullptr, nullptr, 0);
    gemm_k2<64, 1><<<dim3(32, 16), dim3(256), 0, stream>>>(
        attn_ws, wo_bf, bo_bf, out, nullptr, nullptr, nullptr, MM, HH, HH);
}